// Round 4
// baseline (262.256 us; speedup 1.0000x reference)
//
#include <hip/hip_runtime.h>

#define B_ 16
#define L_ 512
#define H_ 256
#define V_ 32000
#define HALF_ 128

typedef __attribute__((ext_vector_type(8))) short short8;
typedef __attribute__((ext_vector_type(4))) float floatx4;

__device__ __forceinline__ unsigned short f2bf(float x) {
  unsigned int u = __float_as_uint(x);
  unsigned int r = (u + 0x7FFFu + ((u >> 16) & 1u)) >> 16;
  return (unsigned short)r;
}

template <int CTRL>
__device__ __forceinline__ float dpp_xor_add(float x) {
  int y = __builtin_amdgcn_mov_dpp(__float_as_int(x), CTRL, 0xf, 0xf, true);
  return x + __int_as_float(y);
}

// butterfly sum over aligned 16-lane groups; ALL lanes get the result
__device__ __forceinline__ float redu16(float p) {
  p = dpp_xor_add<0xB1>(p);   // xor1
  p = dpp_xor_add<0x4E>(p);   // xor2
  p = dpp_xor_add<0x141>(p);  // row_half_mirror
  p = dpp_xor_add<0x140>(p);  // row_mirror
  return p;
}

// full 32-lane-group sum: 16-lane butterfly + xor16 swizzle stage
__device__ __forceinline__ float redu32(float p) {
  p = redu16(p);
  int y = __builtin_amdgcn_ds_swizzle(__float_as_int(p), 0x401F);  // lane ^ 16 within 32-group
  return p + __int_as_float(y);
}

// ---------------- prep: embedding gather (fp32+bf16) + weight bf16 conversion ----------------
__global__ __launch_bounds__(256) void prep_kernel(const int* __restrict__ seq,
                                                   const float* __restrict__ embed,
                                                   float* __restrict__ h,
                                                   unsigned short* __restrict__ hbf,
                                                   const float* __restrict__ W1,
                                                   const float* __restrict__ W2,
                                                   const float* __restrict__ Ws,
                                                   const float* __restrict__ We,
                                                   unsigned short* __restrict__ W1b,
                                                   unsigned short* __restrict__ W2b,
                                                   unsigned short* __restrict__ Wcb) {
  int blk = blockIdx.x;
  int tid = threadIdx.x;
  if (blk < 2048) {
    int token = blk * 4 + (tid >> 6);
    int lane = tid & 63;
    int row = seq[token];
    float4 v = ((const float4*)(embed + (size_t)row * H_))[lane];
    ((float4*)(h + (size_t)token * H_))[lane] = v;
    ushort4 o;
    o.x = f2bf(v.x); o.y = f2bf(v.y); o.z = f2bf(v.z); o.w = f2bf(v.w);
    *(ushort4*)(hbf + (size_t)token * H_ + lane * 4) = o;
  } else {
    int i = (blk - 2048) * 256 + tid;  // 0..327679
    if (i < 131072) W1b[i] = f2bf(W1[i]);
    else if (i < 262144) W2b[i - 131072] = f2bf(W2[i - 131072]);
    else if (i < 294912) Wcb[i - 262144] = f2bf(Ws[i - 262144]);
    else Wcb[i - 262144] = f2bf(We[i - 294912]);
  }
}

// ---------------- bf16 MFMA GEMM with global prefetch: C = act(A @ B^T + bias + Res) ----------------
template <int MT, bool RELU, bool BIAS, bool RES, bool OUT_BF16>
__global__ __launch_bounds__(256) void gemm_mfma(const unsigned short* __restrict__ A,
                                                 const unsigned short* __restrict__ Bw,
                                                 const float* __restrict__ bias,
                                                 const float* __restrict__ Res,
                                                 float* __restrict__ Cf,
                                                 unsigned short* __restrict__ Cb,
                                                 int M, int N, int K) {
  constexpr int FI = MT / 32;
  __shared__ unsigned short As[MT * 40];
  __shared__ unsigned short Bs[128 * 40];
  int tid = threadIdx.x;
  int wave = tid >> 6, lane = tid & 63;
  int wm = (wave >> 1) * (MT / 2), wn = (wave & 1) * 64;
  int quad = lane >> 4, l15 = lane & 15;
  int bm = blockIdx.y * MT, bn = blockIdx.x * 128;
  int sr = tid >> 2, sq = tid & 3;

  floatx4 zero = {0.f, 0.f, 0.f, 0.f};
  floatx4 acc[FI][4];
#pragma unroll
  for (int fi = 0; fi < FI; fi++)
#pragma unroll
    for (int fj = 0; fj < 4; fj++) acc[fi][fj] = zero;

  // prefetch chunk 0
  uint4 av0, av1, bv0, bv1;
  av0 = *(const uint4*)(A + (size_t)(bm + sr) * K + sq * 8);
  if (MT == 128) av1 = *(const uint4*)(A + (size_t)(bm + 64 + sr) * K + sq * 8);
  bv0 = *(const uint4*)(Bw + (size_t)(bn + sr) * K + sq * 8);
  bv1 = *(const uint4*)(Bw + (size_t)(bn + 64 + sr) * K + sq * 8);

  for (int k0 = 0; k0 < K; k0 += 32) {
    __syncthreads();
    *(uint4*)(As + sr * 40 + sq * 8) = av0;
    if (MT == 128) *(uint4*)(As + (64 + sr) * 40 + sq * 8) = av1;
    *(uint4*)(Bs + sr * 40 + sq * 8) = bv0;
    *(uint4*)(Bs + (64 + sr) * 40 + sq * 8) = bv1;
    __syncthreads();
    if (k0 + 32 < K) {  // prefetch next chunk while MFMAs run
      av0 = *(const uint4*)(A + (size_t)(bm + sr) * K + k0 + 32 + sq * 8);
      if (MT == 128) av1 = *(const uint4*)(A + (size_t)(bm + 64 + sr) * K + k0 + 32 + sq * 8);
      bv0 = *(const uint4*)(Bw + (size_t)(bn + sr) * K + k0 + 32 + sq * 8);
      bv1 = *(const uint4*)(Bw + (size_t)(bn + 64 + sr) * K + k0 + 32 + sq * 8);
    }
    short8 af[FI], bf[4];
#pragma unroll
    for (int f = 0; f < FI; f++) af[f] = *(const short8*)(As + (wm + f * 16 + l15) * 40 + quad * 8);
#pragma unroll
    for (int f = 0; f < 4; f++) bf[f] = *(const short8*)(Bs + (wn + f * 16 + l15) * 40 + quad * 8);
#pragma unroll
    for (int fi = 0; fi < FI; fi++)
#pragma unroll
      for (int fj = 0; fj < 4; fj++)
        acc[fi][fj] = __builtin_amdgcn_mfma_f32_16x16x32_bf16(af[fi], bf[fj], acc[fi][fj], 0, 0, 0);
  }

#pragma unroll
  for (int fi = 0; fi < FI; fi++) {
#pragma unroll
    for (int fj = 0; fj < 4; fj++) {
      int col = bn + wn + fj * 16 + l15;
      float bb = BIAS ? bias[col] : 0.f;
#pragma unroll
      for (int rg = 0; rg < 4; rg++) {
        int row = bm + wm + fi * 16 + quad * 4 + rg;
        float v = acc[fi][fj][rg] + bb;
        if (RES) v += Res[(size_t)row * N + col];
        if (RELU) v = fmaxf(v, 0.f);
        if (OUT_BF16) Cb[(size_t)row * N + col] = f2bf(v);
        else Cf[(size_t)row * N + col] = v;
      }
    }
  }
}

// ---------------- LayerNorm over H=256, one wave per row; bf16 output ----------------
__global__ void ln_kernel(const float* __restrict__ x, const float* __restrict__ gamma,
                          const float* __restrict__ beta, unsigned short* __restrict__ yb) {
  int row = blockIdx.x;
  int lane = threadIdx.x;  // 64
  float4 v = ((const float4*)(x + (size_t)row * H_))[lane];
  float s = v.x + v.y + v.z + v.w;
  float sq = v.x * v.x + v.y * v.y + v.z * v.z + v.w * v.w;
#pragma unroll
  for (int off = 32; off >= 1; off >>= 1) {
    s += __shfl_xor(s, off);
    sq += __shfl_xor(sq, off);
  }
  float mu = s * (1.f / H_);
  float var = sq * (1.f / H_) - mu * mu;
  float inv = rsqrtf(var + 1e-5f);
  float4 g = ((const float4*)gamma)[lane];
  float4 b = ((const float4*)beta)[lane];
  ushort4 o;
  o.x = f2bf((v.x - mu) * inv * g.x + b.x);
  o.y = f2bf((v.y - mu) * inv * g.y + b.y);
  o.z = f2bf((v.z - mu) * inv * g.z + b.z);
  o.w = f2bf((v.w - mu) * inv * g.w + b.w);
  *(ushort4*)(yb + (size_t)row * H_ + lane * 4) = o;
}

// ---------------- KPROJ: k = hn @ [Wsem;Wepi]^T; khat fp32 (plain row-major) + raw kT ----------------
__global__ __launch_bounds__(256) void kproj_kernel(const unsigned short* __restrict__ hnb,
                                                    const unsigned short* __restrict__ Wcb,
                                                    float* __restrict__ khat,
                                                    float* __restrict__ kT) {
  __shared__ unsigned short As[32 * 40];
  __shared__ unsigned short Bs[256 * 40];
  int tid = threadIdx.x;
  int wave = tid >> 6, lane = tid & 63;
  int wm = (wave >> 1) * 16, wnh = wave & 1, wn = wnh * 128;
  int quad = lane >> 4, l15 = lane & 15;
  int bm = blockIdx.x * 32;

  floatx4 zero = {0.f, 0.f, 0.f, 0.f};
  floatx4 acc[8];
#pragma unroll
  for (int fj = 0; fj < 8; fj++) acc[fj] = zero;

  int sr = tid >> 2, sq = tid & 3;
  uint4 av, bv[4];
  if (tid < 128) av = *(const uint4*)(hnb + (size_t)(bm + sr) * H_ + sq * 8);
#pragma unroll
  for (int q = 0; q < 4; q++) {
    int unit = q * 256 + tid;
    bv[q] = *(const uint4*)(Wcb + (size_t)(unit >> 2) * H_ + (unit & 3) * 8);
  }

  for (int k0 = 0; k0 < 256; k0 += 32) {
    __syncthreads();
    if (tid < 128) *(uint4*)(As + sr * 40 + sq * 8) = av;
#pragma unroll
    for (int q = 0; q < 4; q++) {
      int unit = q * 256 + tid;
      *(uint4*)(Bs + (unit >> 2) * 40 + (unit & 3) * 8) = bv[q];
    }
    __syncthreads();
    if (k0 + 32 < 256) {
      if (tid < 128) av = *(const uint4*)(hnb + (size_t)(bm + sr) * H_ + k0 + 32 + sq * 8);
#pragma unroll
      for (int q = 0; q < 4; q++) {
        int unit = q * 256 + tid;
        bv[q] = *(const uint4*)(Wcb + (size_t)(unit >> 2) * H_ + k0 + 32 + (unit & 3) * 8);
      }
    }
    short8 af = *(const short8*)(As + (wm + l15) * 40 + quad * 8);
    short8 bf[8];
#pragma unroll
    for (int fj = 0; fj < 8; fj++)
      bf[fj] = *(const short8*)(Bs + (wn + fj * 16 + l15) * 40 + quad * 8);
#pragma unroll
    for (int fj = 0; fj < 8; fj++)
      acc[fj] = __builtin_amdgcn_mfma_f32_16x16x32_bf16(af, bf[fj], acc[fj], 0, 0, 0);
  }

  // epilogue: per-row L2 norm over this wave's 128-col half
  int b = bm >> 9;
  int idxm = b * 2 + wnh;
  int tloc0 = (bm & 511) + wm + quad * 4;
  float inv[4];
#pragma unroll
  for (int rg = 0; rg < 4; rg++) {
    float ssq = 0.f;
#pragma unroll
    for (int fj = 0; fj < 8; fj++) ssq += acc[fj][rg] * acc[fj][rg];
    ssq = redu16(ssq);
    inv[rg] = 1.f / fmaxf(sqrtf(ssq), 1e-12f);
  }
#pragma unroll
  for (int fj = 0; fj < 8; fj++) {
    int ch = fj * 16 + l15;  // logical col 0..127 (khat plain row-major)
#pragma unroll
    for (int rg = 0; rg < 4; rg++)
      khat[((size_t)idxm * L_ + tloc0 + rg) * HALF_ + ch] = acc[fj][rg] * inv[rg];
    float4 raw = {acc[fj][0], acc[fj][1], acc[fj][2], acc[fj][3]};
    *(float4*)(kT + (size_t)idxm * (HALF_ * L_) + (size_t)ch * L_ + tloc0) = raw;
  }
}

// ---------------- scan: 8 rows/block, 32 lanes/row, 2 blocks/CU for TLP ----------------
// Lane layout: rl = tid>>5 (row 0..7), l32 = tid&31, each lane owns cols 4*l32..4*l32+3.
// Per step: p = M[r].khat_t (dot4 + redu32), s = k_t[r] - p, M[r][c] += s*khat_t[c].
// khat chunk staged global->reg->LDS (single buffer, 2 barriers/chunk);
// raw keys LDS-resident for the whole block.
// __launch_bounds__(256, 2): 2 waves/EU target so the allocator keeps the
// nxt[8] staging array in VGPRs (bare (256) capped at 68 VGPR -> 65 MB of
// scratch spill traffic in R3's profile).

#define STEP(PK, KR)                                     \
  do {                                                   \
    float p_ = (m0 * PK.x + m1 * PK.y) + (m2 * PK.z + m3 * PK.w); \
    p_ = redu32(p_);                                     \
    float s_ = (KR) - p_;                                \
    m0 += s_ * PK.x; m1 += s_ * PK.y;                    \
    m2 += s_ * PK.z; m3 += s_ * PK.w;                    \
  } while (0)

__global__ __launch_bounds__(256, 2) void scan_kernel(const float* __restrict__ khat,
                                                      const float* __restrict__ kT,
                                                      float* __restrict__ c) {
  __shared__ float sk[64 * 128];  // 32 KB, one khat chunk
  __shared__ float krs[8 * 512];  // 16 KB, this block's 8 raw-key rows
  int bid = blockIdx.x;
  int idxm = bid & 31;   // matrix 0..31
  int rg = bid >> 5;     // row-group 0..15 (8 rows each)
  int b = idxm >> 1, mat = idxm & 1;
  const float* kh = khat + (size_t)idxm * L_ * HALF_;
  const float* kTi = kT + (size_t)idxm * HALF_ * L_;

  int tid = threadIdx.x;
  int rl = tid >> 5;     // local row 0..7
  int l32 = tid & 31;    // col-lane
  int r = rg * 8 + rl;
  int c0 = l32 * 4;

  float m0 = 0.f, m1 = 0.f, m2 = 0.f, m3 = 0.f;

  // prologue: raw keys (8 rows x 512) + khat chunk 0, reg-staged then LDS
  float4 krv[4], nxt[8];
  {
    const float* gk = kTi + (size_t)rg * 8 * L_;  // rows contiguous
#pragma unroll
    for (int j = 0; j < 4; j++) krv[j] = *(const float4*)(gk + (j * 256 + tid) * 4);
#pragma unroll
    for (int j = 0; j < 8; j++) nxt[j] = *(const float4*)(kh + (j * 256 + tid) * 4);
#pragma unroll
    for (int j = 0; j < 4; j++) *(float4*)(krs + (j * 256 + tid) * 4) = krv[j];
#pragma unroll
    for (int j = 0; j < 8; j++) *(float4*)(sk + (j * 256 + tid) * 4) = nxt[j];
  }
  __syncthreads();

  const float* krp = krs + rl * 512;  // this row's raw-key time series
  const float* base = sk + c0;

  for (int ch = 0; ch < 8; ch++) {
    if (ch < 7) {  // issue next chunk's global loads now; consumed after compute
#pragma unroll
      for (int j = 0; j < 8; j++)
        nxt[j] = *(const float4*)(kh + (size_t)(ch + 1) * 8192 + (j * 256 + tid) * 4);
    }
    const float* krq = krp + ch * 64;
    float4 pk0 = *(const float4*)(base + 0 * 128);
    float4 pk1 = *(const float4*)(base + 1 * 128);
    float4 pk2 = *(const float4*)(base + 2 * 128);
    float4 pk3 = *(const float4*)(base + 3 * 128);
    float4 krn = *(const float4*)(krq);
    for (int g = 0; g < 15; g++) {
      float4 krc = krn;
      krn = *(const float4*)(krq + g * 4 + 4);
      STEP(pk0, krc.x); pk0 = *(const float4*)(base + (g * 4 + 4) * 128);
      STEP(pk1, krc.y); pk1 = *(const float4*)(base + (g * 4 + 5) * 128);
      STEP(pk2, krc.z); pk2 = *(const float4*)(base + (g * 4 + 6) * 128);
      STEP(pk3, krc.w); pk3 = *(const float4*)(base + (g * 4 + 7) * 128);
    }
    {  // last group of the chunk: steps 60..63 (ch<7) or 508..510 (ch==7)
      float4 krc = krn;
      STEP(pk0, krc.x);
      STEP(pk1, krc.y);
      STEP(pk2, krc.z);
      if (ch < 7) STEP(pk3, krc.w);
    }
    __syncthreads();  // all reads of sk done
    if (ch < 7) {
#pragma unroll
      for (int j = 0; j < 8; j++) *(float4*)(sk + (j * 256 + tid) * 4) = nxt[j];
    }
    __syncthreads();  // sk refilled
  }

  // final read with raw last-token key (t=511), gathered from kT columns
  float q0 = kTi[(size_t)(c0 + 0) * L_ + 511];
  float q1 = kTi[(size_t)(c0 + 1) * L_ + 511];
  float q2 = kTi[(size_t)(c0 + 2) * L_ + 511];
  float q3 = kTi[(size_t)(c0 + 3) * L_ + 511];
  float p = redu32((m0 * q0 + m1 * q1) + (m2 * q2 + m3 * q3));
  if (l32 == 0) c[(size_t)b * H_ + mat * HALF_ + r] = p;
}

// ---------------- r = c @ W_rp^T + b_rp ----------------
__global__ void rp_kernel(const float* __restrict__ c, const float* __restrict__ Wrp,
                          const float* __restrict__ brp, float* __restrict__ r) {
  int b = blockIdx.x;
  int n = threadIdx.x;  // 256
  __shared__ float cs[H_];
  cs[n] = c[(size_t)b * H_ + n];
  __syncthreads();
  const float4* w4 = (const float4*)(Wrp + (size_t)n * H_);
  const float4* c4 = (const float4*)cs;
  float acc = 0.f;
#pragma unroll 8
  for (int k = 0; k < H_ / 4; k++) {
    float4 w = w4[k], cc = c4[k];
    acc += w.x * cc.x + w.y * cc.y + w.z * cc.z + w.w * cc.w;
  }
  r[(size_t)b * H_ + n] = acc + brp[n];
}

// ---------------- out = r @ W_out^T + b_out, coalesced ----------------
__global__ __launch_bounds__(256) void out_kernel(const float* __restrict__ r,
                                                  const float* __restrict__ Wout,
                                                  const float* __restrict__ bout,
                                                  float* __restrict__ out) {
  __shared__ float rs[16 * 272];
  __shared__ float obuf[16 * 68];
  int tid = threadIdx.x;
#pragma unroll
  for (int q = 0; q < 16; q++) {
    int idx = q * 256 + tid;
    int bb = idx >> 8, cc = idx & 255;
    rs[bb * 272 + cc + 4 * (cc >> 6)] = r[idx];
  }
  __syncthreads();
  int row = tid >> 2, part = tid & 3;
  int v = blockIdx.x * 64 + row;
  const float4* w4 = (const float4*)(Wout + (size_t)v * H_ + part * 64);
  float acc[16];
#pragma unroll
  for (int bb = 0; bb < 16; bb++) acc[bb] = 0.f;
#pragma unroll 4
  for (int j = 0; j < 16; j++) {
    float4 w = w4[j];
#pragma unroll
    for (int bb = 0; bb < 16; bb++) {
      float4 rv = *(const float4*)&rs[bb * 272 + part * 68 + j * 4];
      acc[bb] += w.x * rv.x + w.y * rv.y + w.z * rv.z + w.w * rv.w;
    }
  }
  float bo = bout[v];
#pragma unroll
  for (int bb = 0; bb < 16; bb++) {
    acc[bb] = dpp_xor_add<0xB1>(acc[bb]);
    acc[bb] = dpp_xor_add<0x4E>(acc[bb]);
  }
#pragma unroll
  for (int q = 0; q < 4; q++) {
    int bb = part * 4 + q;
    obuf[bb * 68 + row] = acc[bb] + bo;
  }
  __syncthreads();
#pragma unroll
  for (int q = 0; q < 4; q++) {
    int idx = q * 256 + tid;
    int bb = idx >> 6, vl = idx & 63;
    out[(size_t)bb * V_ + blockIdx.x * 64 + vl] = obuf[bb * 68 + vl];
  }
}

extern "C" void kernel_launch(void* const* d_in, const int* in_sizes, int n_in,
                              void* d_out, int out_size, void* d_ws, size_t ws_size,
                              hipStream_t stream) {
  const int* seq = (const int*)d_in[0];
  const float* embed = (const float*)d_in[1];
  const float* W1 = (const float*)d_in[2];
  const float* b1 = (const float*)d_in[3];
  const float* W2 = (const float*)d_in[4];
  const float* b2 = (const float*)d_in[5];
  const float* gamma = (const float*)d_in[6];
  const float* beta = (const float*)d_in[7];
  const float* Wsem = (const float*)d_in[8];
  const float* Wepi = (const float*)d_in[9];
  const float* Wrp = (const float*)d_in[10];
  const float* brp = (const float*)d_in[11];
  const float* Wout = (const float*)d_in[12];
  const float* bout = (const float*)d_in[13];
  float* out = (float*)d_out;

  // Workspace layout (float-slot offsets), NO overlapping live ranges:
  //  [0        , 2097152 )  h fp32 (x in-place)  -> later kT (h dead after ln)
  //  [2097152  , 4194304 )  a1b bf16 [8192,512]  -> later khat (a1b dead after gemm2)
  //  [4194304  , 5242880 )  hbf bf16 [8192,256]
  //  [5242880  , 6291456 )  hnb bf16 [8192,256]
  //  [6291456  , 6356992 )  W1b bf16 131072
  //  [6356992  , 6422528 )  W2b bf16 131072
  //  [6422528  , 6455296 )  Wcb bf16 65536
  //  [6455296  , 6459392 )  c  [16,256]
  //  [6459392  , 6463488 )  r  [16,256]
  float* ws = (float*)d_ws;
  float* h = ws;
  float* kT = ws;
  unsigned short* a1b = (unsigned short*)(ws + 2097152);
  float* khat = ws + 2097152;
  unsigned short* hbf = (unsigned short*)(ws + 4194304);
  unsigned short* hnb = (unsigned short*)(ws + 5242880);
  unsigned short* W1b = (unsigned short*)(ws + 6291456);
  unsigned short* W2b = (unsigned short*)(ws + 6356992);
  unsigned short* Wcb = (unsigned short*)(ws + 6422528);
  float* c = ws + 6455296;
  float* r = ws + 6459392;

  // 1. gather (h fp32 + hbf bf16) + weight conversion
  prep_kernel<<<3328, 256, 0, stream>>>(seq, embed, h, hbf, W1, W2, Wsem, Wepi, W1b, W2b, Wcb);
  // 2. a1 = relu(h @ W1^T + b1) -> bf16
  gemm_mfma<128, true, true, false, true><<<dim3(4, 64), 256, 0, stream>>>(
      hbf, W1b, b1, nullptr, nullptr, a1b, 8192, 512, 256);
  // 3. x = a1 @ W2^T + b2 + h -> fp32 in-place over h
  gemm_mfma<64, false, true, true, false><<<dim3(2, 128), 256, 0, stream>>>(
      a1b, W2b, b2, h, h, nullptr, 8192, 256, 512);
  // 4. hn = LayerNorm(x) -> bf16
  ln_kernel<<<8192, 64, 0, stream>>>(h, gamma, beta, hnb);
  // 5. k-projection + normalize + transpose (khat over a1b, kT over h)
  kproj_kernel<<<256, 256, 0, stream>>>(hnb, Wcb, khat, kT);
  // 6. delta-rule scan -> c [16,256]  (512 blocks: 32 matrices x 16 row-groups)
  scan_kernel<<<512, 256, 0, stream>>>(khat, kT, c);
  // 7. r = c @ Wrp^T + brp
  rp_kernel<<<16, 256, 0, stream>>>(c, Wrp, brp, r);
  // 8. out = r @ Wout^T + bout
  out_kernel<<<500, 256, 0, stream>>>(r, Wout, bout, out);
}

// Round 6
// 227.343 us; speedup vs baseline: 1.1536x; 1.1536x over previous
//
#include <hip/hip_runtime.h>

#define B_ 16
#define L_ 512
#define H_ 256
#define V_ 32000
#define HALF_ 128

typedef __attribute__((ext_vector_type(8))) short short8;
typedef __attribute__((ext_vector_type(4))) float floatx4;

__device__ __forceinline__ unsigned short f2bf(float x) {
  unsigned int u = __float_as_uint(x);
  unsigned int r = (u + 0x7FFFu + ((u >> 16) & 1u)) >> 16;
  return (unsigned short)r;
}

template <int CTRL>
__device__ __forceinline__ float dpp_xor_add(float x) {
  int y = __builtin_amdgcn_mov_dpp(__float_as_int(x), CTRL, 0xf, 0xf, true);
  return x + __int_as_float(y);
}

// butterfly sum over aligned 16-lane groups; ALL lanes get the result
__device__ __forceinline__ float redu16(float p) {
  p = dpp_xor_add<0xB1>(p);   // xor1
  p = dpp_xor_add<0x4E>(p);   // xor2
  p = dpp_xor_add<0x141>(p);  // row_half_mirror
  p = dpp_xor_add<0x140>(p);  // row_mirror
  return p;
}

// async global->LDS copy, 16B per lane, wave-uniform LDS base
__device__ __forceinline__ void async_cp16(const float* g, float* l) {
  __builtin_amdgcn_global_load_lds(
      (const __attribute__((address_space(1))) void*)g,
      (__attribute__((address_space(3))) void*)l, 16, 0, 0);
}

// ---------------- prep: embedding gather (fp32+bf16) + weight bf16 conversion ----------------
__global__ __launch_bounds__(256) void prep_kernel(const int* __restrict__ seq,
                                                   const float* __restrict__ embed,
                                                   float* __restrict__ h,
                                                   unsigned short* __restrict__ hbf,
                                                   const float* __restrict__ W1,
                                                   const float* __restrict__ W2,
                                                   const float* __restrict__ Ws,
                                                   const float* __restrict__ We,
                                                   unsigned short* __restrict__ W1b,
                                                   unsigned short* __restrict__ W2b,
                                                   unsigned short* __restrict__ Wcb) {
  int blk = blockIdx.x;
  int tid = threadIdx.x;
  if (blk < 2048) {
    int token = blk * 4 + (tid >> 6);
    int lane = tid & 63;
    int row = seq[token];
    float4 v = ((const float4*)(embed + (size_t)row * H_))[lane];
    ((float4*)(h + (size_t)token * H_))[lane] = v;
    ushort4 o;
    o.x = f2bf(v.x); o.y = f2bf(v.y); o.z = f2bf(v.z); o.w = f2bf(v.w);
    *(ushort4*)(hbf + (size_t)token * H_ + lane * 4) = o;
  } else {
    int i = (blk - 2048) * 256 + tid;  // 0..327679
    if (i < 131072) W1b[i] = f2bf(W1[i]);
    else if (i < 262144) W2b[i - 131072] = f2bf(W2[i - 131072]);
    else if (i < 294912) Wcb[i - 262144] = f2bf(Ws[i - 262144]);
    else Wcb[i - 262144] = f2bf(We[i - 294912]);
  }
}

// ---------------- bf16 MFMA GEMM with global prefetch: C = act(A @ B^T + bias + Res) ----------------
template <int MT, bool RELU, bool BIAS, bool RES, bool OUT_BF16>
__global__ __launch_bounds__(256) void gemm_mfma(const unsigned short* __restrict__ A,
                                                 const unsigned short* __restrict__ Bw,
                                                 const float* __restrict__ bias,
                                                 const float* __restrict__ Res,
                                                 float* __restrict__ Cf,
                                                 unsigned short* __restrict__ Cb,
                                                 int M, int N, int K) {
  constexpr int FI = MT / 32;
  __shared__ unsigned short As[MT * 40];
  __shared__ unsigned short Bs[128 * 40];
  int tid = threadIdx.x;
  int wave = tid >> 6, lane = tid & 63;
  int wm = (wave >> 1) * (MT / 2), wn = (wave & 1) * 64;
  int quad = lane >> 4, l15 = lane & 15;
  int bm = blockIdx.y * MT, bn = blockIdx.x * 128;
  int sr = tid >> 2, sq = tid & 3;

  floatx4 zero = {0.f, 0.f, 0.f, 0.f};
  floatx4 acc[FI][4];
#pragma unroll
  for (int fi = 0; fi < FI; fi++)
#pragma unroll
    for (int fj = 0; fj < 4; fj++) acc[fi][fj] = zero;

  // prefetch chunk 0
  uint4 av0, av1, bv0, bv1;
  av0 = *(const uint4*)(A + (size_t)(bm + sr) * K + sq * 8);
  if (MT == 128) av1 = *(const uint4*)(A + (size_t)(bm + 64 + sr) * K + sq * 8);
  bv0 = *(const uint4*)(Bw + (size_t)(bn + sr) * K + sq * 8);
  bv1 = *(const uint4*)(Bw + (size_t)(bn + 64 + sr) * K + sq * 8);

  for (int k0 = 0; k0 < K; k0 += 32) {
    __syncthreads();
    *(uint4*)(As + sr * 40 + sq * 8) = av0;
    if (MT == 128) *(uint4*)(As + (64 + sr) * 40 + sq * 8) = av1;
    *(uint4*)(Bs + sr * 40 + sq * 8) = bv0;
    *(uint4*)(Bs + (64 + sr) * 40 + sq * 8) = bv1;
    __syncthreads();
    if (k0 + 32 < K) {  // prefetch next chunk while MFMAs run
      av0 = *(const uint4*)(A + (size_t)(bm + sr) * K + k0 + 32 + sq * 8);
      if (MT == 128) av1 = *(const uint4*)(A + (size_t)(bm + 64 + sr) * K + k0 + 32 + sq * 8);
      bv0 = *(const uint4*)(Bw + (size_t)(bn + sr) * K + k0 + 32 + sq * 8);
      bv1 = *(const uint4*)(Bw + (size_t)(bn + 64 + sr) * K + k0 + 32 + sq * 8);
    }
    short8 af[FI], bf[4];
#pragma unroll
    for (int f = 0; f < FI; f++) af[f] = *(const short8*)(As + (wm + f * 16 + l15) * 40 + quad * 8);
#pragma unroll
    for (int f = 0; f < 4; f++) bf[f] = *(const short8*)(Bs + (wn + f * 16 + l15) * 40 + quad * 8);
#pragma unroll
    for (int fi = 0; fi < FI; fi++)
#pragma unroll
      for (int fj = 0; fj < 4; fj++)
        acc[fi][fj] = __builtin_amdgcn_mfma_f32_16x16x32_bf16(af[fi], bf[fj], acc[fi][fj], 0, 0, 0);
  }

#pragma unroll
  for (int fi = 0; fi < FI; fi++) {
#pragma unroll
    for (int fj = 0; fj < 4; fj++) {
      int col = bn + wn + fj * 16 + l15;
      float bb = BIAS ? bias[col] : 0.f;
#pragma unroll
      for (int rg = 0; rg < 4; rg++) {
        int row = bm + wm + fi * 16 + quad * 4 + rg;
        float v = acc[fi][fj][rg] + bb;
        if (RES) v += Res[(size_t)row * N + col];
        if (RELU) v = fmaxf(v, 0.f);
        if (OUT_BF16) Cb[(size_t)row * N + col] = f2bf(v);
        else Cf[(size_t)row * N + col] = v;
      }
    }
  }
}

// ---------------- KPROJ with fused LayerNorm:
// hn = LN(x); k = hn @ [Wsem;Wepi]^T; khat fp32 (granule-permuted) + raw kT ----------------
// LN stats computed in a prologue (8 threads/row, DPP reduce); normalization applied
// during the fp32->bf16 As staging. Replaces the separate ln_kernel dispatch.
__global__ __launch_bounds__(256) void kproj_kernel(const float* __restrict__ hx,
                                                    const float* __restrict__ gma,
                                                    const float* __restrict__ bta,
                                                    const unsigned short* __restrict__ Wcb,
                                                    float* __restrict__ khat,
                                                    float* __restrict__ kT) {
  __shared__ unsigned short As[32 * 40];
  __shared__ unsigned short Bs[256 * 40];
  __shared__ float mus[32], ivs[32];
  int tid = threadIdx.x;
  int wave = tid >> 6, lane = tid & 63;
  int wm = (wave >> 1) * 16, wnh = wave & 1, wn = wnh * 128;
  int quad = lane >> 4, l15 = lane & 15;
  int bm = blockIdx.x * 32;

  // ---- LN stats for rows bm..bm+31 (8 threads per row; 8-lane DPP reduce)
  {
    int row = tid >> 3, jj = tid & 7;
    const float4* hr = (const float4*)(hx + (size_t)(bm + row) * H_ + jj * 32);
    float s = 0.f, sq = 0.f;
#pragma unroll
    for (int q = 0; q < 8; q++) {
      float4 v = hr[q];
      s += (v.x + v.y) + (v.z + v.w);
      sq += (v.x * v.x + v.y * v.y) + (v.z * v.z + v.w * v.w);
    }
    s = dpp_xor_add<0xB1>(s);  sq = dpp_xor_add<0xB1>(sq);
    s = dpp_xor_add<0x4E>(s);  sq = dpp_xor_add<0x4E>(sq);
    s = dpp_xor_add<0x141>(s); sq = dpp_xor_add<0x141>(sq);
    float mu = s * (1.f / H_);
    float var = sq * (1.f / H_) - mu * mu;
    if (jj == 0) { mus[row] = mu; ivs[row] = rsqrtf(var + 1e-5f); }
  }
  // mus/ivs are ordered before As staging by the loop-top __syncthreads().

  floatx4 zero = {0.f, 0.f, 0.f, 0.f};
  floatx4 acc[8];
#pragma unroll
  for (int fj = 0; fj < 8; fj++) acc[fj] = zero;

  int sr = tid >> 2, sq4 = tid & 3;
  // prefetch chunk 0: A fp32 + gamma/beta (per-column) + B bf16
  float4 af0, af1, gf0, gf1, bt0, bt1;
  uint4 bv[4];
  if (tid < 128) {
    const float4* ap = (const float4*)(hx + (size_t)(bm + sr) * H_ + sq4 * 8);
    af0 = ap[0]; af1 = ap[1];
    const float4* gp = (const float4*)(gma + sq4 * 8); gf0 = gp[0]; gf1 = gp[1];
    const float4* bp = (const float4*)(bta + sq4 * 8); bt0 = bp[0]; bt1 = bp[1];
  }
#pragma unroll
  for (int q = 0; q < 4; q++) {
    int unit = q * 256 + tid;
    bv[q] = *(const uint4*)(Wcb + (size_t)(unit >> 2) * H_ + (unit & 3) * 8);
  }

  for (int k0 = 0; k0 < 256; k0 += 32) {
    __syncthreads();
    if (tid < 128) {  // normalize + cast + stage A
      float mu = mus[sr], iv = ivs[sr];
      ushort4 lo, hi;
      lo.x = f2bf((af0.x - mu) * iv * gf0.x + bt0.x);
      lo.y = f2bf((af0.y - mu) * iv * gf0.y + bt0.y);
      lo.z = f2bf((af0.z - mu) * iv * gf0.z + bt0.z);
      lo.w = f2bf((af0.w - mu) * iv * gf0.w + bt0.w);
      hi.x = f2bf((af1.x - mu) * iv * gf1.x + bt1.x);
      hi.y = f2bf((af1.y - mu) * iv * gf1.y + bt1.y);
      hi.z = f2bf((af1.z - mu) * iv * gf1.z + bt1.z);
      hi.w = f2bf((af1.w - mu) * iv * gf1.w + bt1.w);
      *(ushort4*)(As + sr * 40 + sq4 * 8) = lo;
      *(ushort4*)(As + sr * 40 + sq4 * 8 + 4) = hi;
    }
#pragma unroll
    for (int q = 0; q < 4; q++) {
      int unit = q * 256 + tid;
      *(uint4*)(Bs + (unit >> 2) * 40 + (unit & 3) * 8) = bv[q];
    }
    __syncthreads();
    if (k0 + 32 < 256) {
      if (tid < 128) {
        const float4* ap = (const float4*)(hx + (size_t)(bm + sr) * H_ + k0 + 32 + sq4 * 8);
        af0 = ap[0]; af1 = ap[1];
        const float4* gp = (const float4*)(gma + k0 + 32 + sq4 * 8); gf0 = gp[0]; gf1 = gp[1];
        const float4* bp = (const float4*)(bta + k0 + 32 + sq4 * 8); bt0 = bp[0]; bt1 = bp[1];
      }
#pragma unroll
      for (int q = 0; q < 4; q++) {
        int unit = q * 256 + tid;
        bv[q] = *(const uint4*)(Wcb + (size_t)(unit >> 2) * H_ + k0 + 32 + (unit & 3) * 8);
      }
    }
    short8 af = *(const short8*)(As + (wm + l15) * 40 + quad * 8);
    short8 bf[8];
#pragma unroll
    for (int fj = 0; fj < 8; fj++)
      bf[fj] = *(const short8*)(Bs + (wn + fj * 16 + l15) * 40 + quad * 8);
#pragma unroll
    for (int fj = 0; fj < 8; fj++)
      acc[fj] = __builtin_amdgcn_mfma_f32_16x16x32_bf16(af, bf[fj], acc[fj], 0, 0, 0);
  }

  // epilogue: per-row L2 norm over this wave's 128-col half
  int b = bm >> 9;
  int idxm = b * 2 + wnh;
  int tloc0 = (bm & 511) + wm + quad * 4;
  float inv[4];
#pragma unroll
  for (int rg = 0; rg < 4; rg++) {
    float ssq = 0.f;
#pragma unroll
    for (int fj = 0; fj < 8; fj++) ssq += acc[fj][rg] * acc[fj][rg];
    ssq = redu16(ssq);
    inv[rg] = 1.f / fmaxf(sqrtf(ssq), 1e-12f);
  }
#pragma unroll
  for (int fj = 0; fj < 8; fj++) {
    int ch = fj * 16 + l15;             // logical col 0..127
    int j = ch >> 2, e = ch & 3;        // float4 granule + elem
    int pj = (j & 1) ? (16 + (j >> 1)) : (j >> 1);  // even granules first
    int pcol = pj * 4 + e;
#pragma unroll
    for (int rg = 0; rg < 4; rg++)
      khat[((size_t)idxm * L_ + tloc0 + rg) * HALF_ + pcol] = acc[fj][rg] * inv[rg];
    float4 raw = {acc[fj][0], acc[fj][1], acc[fj][2], acc[fj][3]};
    *(float4*)(kT + (size_t)idxm * (HALF_ * L_) + (size_t)ch * L_ + tloc0) = raw;
  }
}

// ---------------- scan: LDS-staged khat (async), 4-deep ds_read ring (R0-proven) ----------------
#define STEP(KP, KR)                                                     \
  do {                                                                   \
    float t0_ = m[0] * KP[0] + m[1] * KP[1];                             \
    float t1_ = m[2] * KP[2] + m[3] * KP[3];                             \
    float t2_ = m[4] * KP[4] + m[5] * KP[5];                             \
    float t3_ = m[6] * KP[6] + m[7] * KP[7];                             \
    float p_ = (t0_ + t1_) + (t2_ + t3_);                                \
    p_ = redu16(p_);                                                     \
    float s_ = (KR) - p_;                                                \
    m[0] += s_ * KP[0]; m[1] += s_ * KP[1]; m[2] += s_ * KP[2];          \
    m[3] += s_ * KP[3]; m[4] += s_ * KP[4]; m[5] += s_ * KP[5];          \
    m[6] += s_ * KP[6]; m[7] += s_ * KP[7];                              \
  } while (0)

__global__ __launch_bounds__(256) void scan_kernel(const float* __restrict__ khat,
                                                   const float* __restrict__ kT,
                                                   float* __restrict__ c) {
  __shared__ float sk[2][64 * 128];  // 2 x 32 KB double buffer
  int bid = blockIdx.x;
  int idxm = bid & 31;
  int rg = bid >> 5;
  int b = idxm >> 1, mat = idxm & 1;
  const float* kh = khat + (size_t)idxm * L_ * HALF_;
  const float* kTi = kT + (size_t)idxm * HALF_ * L_;

  int tid = threadIdx.x;
  int wave = tid >> 6, lane = tid & 63;
  int seg = tid & 15, rl = tid >> 4;
  int r = rg * 16 + rl;
  int c0 = seg * 8;
  const float* krow = kTi + (size_t)r * L_;

  float m[8];
#pragma unroll
  for (int g = 0; g < 8; g++) m[g] = 0.f;

  // stage chunk 0 into buf 0
  {
    const float* g0 = kh + wave * 2048 + lane * 4;
    float* l0 = &sk[0][wave * 2048];
#pragma unroll
    for (int j = 0; j < 8; j++) async_cp16(g0 + j * 256, l0 + j * 256);
  }
  __syncthreads();

  float4 krn = *(const float4*)(krow);  // raw keys, steps 0..3
  const float* lb = &sk[0][0] + seg * 4;

  // chunks 0..6 (full 64 steps each)
  for (int ch = 0; ch < 7; ch++) {
    {  // stage chunk ch+1 into the other buffer (async, drains at end-of-chunk barrier)
      const float* gs = kh + (size_t)(ch + 1) * 8192 + wave * 2048 + lane * 4;
      float* ls = &sk[(ch + 1) & 1][wave * 2048];
#pragma unroll
      for (int j = 0; j < 8; j++) async_cp16(gs + j * 256, ls + j * 256);
    }
    const float* base = lb + (ch & 1) * 8192;
    float pk[4][8];
#pragma unroll
    for (int u = 0; u < 4; u++) {
      *(float4*)&pk[u][0] = *(const float4*)(base + u * 128);
      *(float4*)&pk[u][4] = *(const float4*)(base + u * 128 + 64);
    }
    for (int g = 0; g < 15; g++) {
      float4 krc = krn;
      krn = *(const float4*)(krow + ch * 64 + g * 4 + 4);
#pragma unroll
      for (int u = 0; u < 4; u++) {
        STEP(pk[u], ((u == 0) ? krc.x : (u == 1) ? krc.y : (u == 2) ? krc.z : krc.w));
        int tn = g * 4 + u + 4;
        *(float4*)&pk[u][0] = *(const float4*)(base + tn * 128);
        *(float4*)&pk[u][4] = *(const float4*)(base + tn * 128 + 64);
      }
    }
    {  // last 4 steps of chunk, no prefetch
      float4 krc = krn;
      krn = *(const float4*)(krow + ch * 64 + 64);
      STEP(pk[0], krc.x);
      STEP(pk[1], krc.y);
      STEP(pk[2], krc.z);
      STEP(pk[3], krc.w);
    }
    __syncthreads();
  }

  // chunk 7: steps 448..510 (63 updates)
  {
    const float* base = lb + 8192;  // buf 1
    float pk[4][8];
#pragma unroll
    for (int u = 0; u < 4; u++) {
      *(float4*)&pk[u][0] = *(const float4*)(base + u * 128);
      *(float4*)&pk[u][4] = *(const float4*)(base + u * 128 + 64);
    }
    for (int g = 0; g < 15; g++) {
      float4 krc = krn;
      krn = *(const float4*)(krow + 448 + g * 4 + 4);
#pragma unroll
      for (int u = 0; u < 4; u++) {
        STEP(pk[u], ((u == 0) ? krc.x : (u == 1) ? krc.y : (u == 2) ? krc.z : krc.w));
        int tn = g * 4 + u + 4;
        *(float4*)&pk[u][0] = *(const float4*)(base + tn * 128);
        *(float4*)&pk[u][4] = *(const float4*)(base + tn * 128 + 64);
      }
    }
    float4 krc = krn;  // raw keys for steps 508..511
    STEP(pk[0], krc.x);  // 508
    STEP(pk[1], krc.y);  // 509
    STEP(pk[2], krc.z);  // 510
  }

  // final read with raw last-token key (t=511), gathered from kT columns
  float q[8];
#pragma unroll
  for (int j = 0; j < 8; j++) q[j] = kTi[(size_t)(c0 + j) * L_ + 511];
  float t0 = m[0] * q[0] + m[1] * q[1];
  float t1 = m[2] * q[2] + m[3] * q[3];
  float t2 = m[4] * q[4] + m[5] * q[5];
  float t3 = m[6] * q[6] + m[7] * q[7];
  float p = redu16((t0 + t1) + (t2 + t3));
  if (seg == 0) c[(size_t)b * H_ + mat * HALF_ + r] = p;
}

// ---------------- r = c @ W_rp^T + b_rp ----------------
__global__ void rp_kernel(const float* __restrict__ c, const float* __restrict__ Wrp,
                          const float* __restrict__ brp, float* __restrict__ r) {
  int b = blockIdx.x;
  int n = threadIdx.x;  // 256
  __shared__ float cs[H_];
  cs[n] = c[(size_t)b * H_ + n];
  __syncthreads();
  const float4* w4 = (const float4*)(Wrp + (size_t)n * H_);
  const float4* c4 = (const float4*)cs;
  float acc = 0.f;
#pragma unroll 8
  for (int k = 0; k < H_ / 4; k++) {
    float4 w = w4[k], cc = c4[k];
    acc += w.x * cc.x + w.y * cc.y + w.z * cc.z + w.w * cc.w;
  }
  r[(size_t)b * H_ + n] = acc + brp[n];
}

// ---------------- out = r @ W_out^T + b_out, coalesced ----------------
__global__ __launch_bounds__(256) void out_kernel(const float* __restrict__ r,
                                                  const float* __restrict__ Wout,
                                                  const float* __restrict__ bout,
                                                  float* __restrict__ out) {
  __shared__ float rs[16 * 272];
  __shared__ float obuf[16 * 68];
  int tid = threadIdx.x;
#pragma unroll
  for (int q = 0; q < 16; q++) {
    int idx = q * 256 + tid;
    int bb = idx >> 8, cc = idx & 255;
    rs[bb * 272 + cc + 4 * (cc >> 6)] = r[idx];
  }
  __syncthreads();
  int row = tid >> 2, part = tid & 3;
  int v = blockIdx.x * 64 + row;
  const float4* w4 = (const float4*)(Wout + (size_t)v * H_ + part * 64);
  float acc[16];
#pragma unroll
  for (int bb = 0; bb < 16; bb++) acc[bb] = 0.f;
#pragma unroll 4
  for (int j = 0; j < 16; j++) {
    float4 w = w4[j];
#pragma unroll
    for (int bb = 0; bb < 16; bb++) {
      float4 rv = *(const float4*)&rs[bb * 272 + part * 68 + j * 4];
      acc[bb] += w.x * rv.x + w.y * rv.y + w.z * rv.z + w.w * rv.w;
    }
  }
  float bo = bout[v];
#pragma unroll
  for (int bb = 0; bb < 16; bb++) {
    acc[bb] = dpp_xor_add<0xB1>(acc[bb]);
    acc[bb] = dpp_xor_add<0x4E>(acc[bb]);
  }
#pragma unroll
  for (int q = 0; q < 4; q++) {
    int bb = part * 4 + q;
    obuf[bb * 68 + row] = acc[bb] + bo;
  }
  __syncthreads();
#pragma unroll
  for (int q = 0; q < 4; q++) {
    int idx = q * 256 + tid;
    int bb = idx >> 6, vl = idx & 63;
    out[(size_t)bb * V_ + blockIdx.x * 64 + vl] = obuf[bb * 68 + vl];
  }
}

extern "C" void kernel_launch(void* const* d_in, const int* in_sizes, int n_in,
                              void* d_out, int out_size, void* d_ws, size_t ws_size,
                              hipStream_t stream) {
  const int* seq = (const int*)d_in[0];
  const float* embed = (const float*)d_in[1];
  const float* W1 = (const float*)d_in[2];
  const float* b1 = (const float*)d_in[3];
  const float* W2 = (const float*)d_in[4];
  const float* b2 = (const float*)d_in[5];
  const float* gamma = (const float*)d_in[6];
  const float* beta = (const float*)d_in[7];
  const float* Wsem = (const float*)d_in[8];
  const float* Wepi = (const float*)d_in[9];
  const float* Wrp = (const float*)d_in[10];
  const float* brp = (const float*)d_in[11];
  const float* Wout = (const float*)d_in[12];
  const float* bout = (const float*)d_in[13];
  float* out = (float*)d_out;

  // Workspace layout (float-slot offsets), NO overlapping live ranges:
  //  [0        , 2097152 )  h fp32 (x in-place)  -> later kT (h dead after kproj)
  //  [2097152  , 4194304 )  a1b bf16 [8192,512]  -> later khat (a1b dead after gemm2)
  //  [4194304  , 5242880 )  hbf bf16 [8192,256]
  //  [6291456  , 6356992 )  W1b bf16 131072
  //  [6356992  , 6422528 )  W2b bf16 131072
  //  [6422528  , 6455296 )  Wcb bf16 65536
  //  [6455296  , 6459392 )  c  [16,256]
  //  [6459392  , 6463488 )  r  [16,256]
  float* ws = (float*)d_ws;
  float* h = ws;
  float* kT = ws;
  unsigned short* a1b = (unsigned short*)(ws + 2097152);
  float* khat = ws + 2097152;
  unsigned short* hbf = (unsigned short*)(ws + 4194304);
  unsigned short* W1b = (unsigned short*)(ws + 6291456);
  unsigned short* W2b = (unsigned short*)(ws + 6356992);
  unsigned short* Wcb = (unsigned short*)(ws + 6422528);
  float* c = ws + 6455296;
  float* r = ws + 6459392;

  // 1. gather (h fp32 + hbf bf16) + weight conversion
  prep_kernel<<<3328, 256, 0, stream>>>(seq, embed, h, hbf, W1, W2, Wsem, Wepi, W1b, W2b, Wcb);
  // 2. a1 = relu(h @ W1^T + b1) -> bf16
  gemm_mfma<128, true, true, false, true><<<dim3(4, 64), 256, 0, stream>>>(
      hbf, W1b, b1, nullptr, nullptr, a1b, 8192, 512, 256);
  // 3. x = a1 @ W2^T + b2 + h -> fp32 in-place over h
  gemm_mfma<64, false, true, true, false><<<dim3(2, 128), 256, 0, stream>>>(
      a1b, W2b, b2, h, h, nullptr, 8192, 256, 512);
  // 4+5. fused LayerNorm + k-projection + normalize + permute/transpose
  kproj_kernel<<<256, 256, 0, stream>>>(h, gamma, beta, Wcb, khat, kT);
  // 6. delta-rule scan -> c [16,256]
  scan_kernel<<<256, 256, 0, stream>>>(khat, kT, c);
  // 7. r = c @ Wrp^T + brp
  rp_kernel<<<16, 256, 0, stream>>>(c, Wrp, brp, r);
  // 8. out = r @ Wout^T + bout
  out_kernel<<<500, 256, 0, stream>>>(r, Wout, bout, out);
}

// Round 8
// 222.854 us; speedup vs baseline: 1.1768x; 1.0201x over previous
//
#include <hip/hip_runtime.h>

#define B_ 16
#define L_ 512
#define H_ 256
#define V_ 32000
#define HALF_ 128

typedef __attribute__((ext_vector_type(8))) short short8;
typedef __attribute__((ext_vector_type(4))) float floatx4;

__device__ __forceinline__ unsigned short f2bf(float x) {
  unsigned int u = __float_as_uint(x);
  unsigned int r = (u + 0x7FFFu + ((u >> 16) & 1u)) >> 16;
  return (unsigned short)r;
}

template <int CTRL>
__device__ __forceinline__ float dpp_xor_add(float x) {
  int y = __builtin_amdgcn_mov_dpp(__float_as_int(x), CTRL, 0xf, 0xf, true);
  return x + __int_as_float(y);
}

// butterfly sum over aligned 16-lane groups; ALL lanes get the result
__device__ __forceinline__ float redu16(float p) {
  p = dpp_xor_add<0xB1>(p);   // xor1
  p = dpp_xor_add<0x4E>(p);   // xor2
  p = dpp_xor_add<0x141>(p);  // row_half_mirror
  p = dpp_xor_add<0x140>(p);  // row_mirror
  return p;
}

// async global->LDS copy, 16B per lane, wave-uniform LDS base
__device__ __forceinline__ void async_cp16(const float* g, float* l) {
  __builtin_amdgcn_global_load_lds(
      (const __attribute__((address_space(1))) void*)g,
      (__attribute__((address_space(3))) void*)l, 16, 0, 0);
}

// ---------------- prep: embedding gather (fp32+bf16) + weight bf16 conversion ----------------
__global__ __launch_bounds__(256) void prep_kernel(const int* __restrict__ seq,
                                                   const float* __restrict__ embed,
                                                   float* __restrict__ h,
                                                   unsigned short* __restrict__ hbf,
                                                   const float* __restrict__ W1,
                                                   const float* __restrict__ W2,
                                                   const float* __restrict__ Ws,
                                                   const float* __restrict__ We,
                                                   unsigned short* __restrict__ W1b,
                                                   unsigned short* __restrict__ W2b,
                                                   unsigned short* __restrict__ Wcb) {
  int blk = blockIdx.x;
  int tid = threadIdx.x;
  if (blk < 2048) {
    int token = blk * 4 + (tid >> 6);
    int lane = tid & 63;
    int row = seq[token];
    float4 v = ((const float4*)(embed + (size_t)row * H_))[lane];
    ((float4*)(h + (size_t)token * H_))[lane] = v;
    ushort4 o;
    o.x = f2bf(v.x); o.y = f2bf(v.y); o.z = f2bf(v.z); o.w = f2bf(v.w);
    *(ushort4*)(hbf + (size_t)token * H_ + lane * 4) = o;
  } else {
    int i = (blk - 2048) * 256 + tid;  // 0..327679
    if (i < 131072) W1b[i] = f2bf(W1[i]);
    else if (i < 262144) W2b[i - 131072] = f2bf(W2[i - 131072]);
    else if (i < 294912) Wcb[i - 262144] = f2bf(Ws[i - 262144]);
    else Wcb[i - 262144] = f2bf(We[i - 294912]);
  }
}

// ---------------- bf16 MFMA GEMM with global prefetch: C = act(A @ B^T + bias + Res) ----------------
template <int MT, bool RELU, bool BIAS, bool RES, bool OUT_BF16>
__global__ __launch_bounds__(256) void gemm_mfma(const unsigned short* __restrict__ A,
                                                 const unsigned short* __restrict__ Bw,
                                                 const float* __restrict__ bias,
                                                 const float* __restrict__ Res,
                                                 float* __restrict__ Cf,
                                                 unsigned short* __restrict__ Cb,
                                                 int M, int N, int K) {
  constexpr int FI = MT / 32;
  __shared__ unsigned short As[MT * 40];
  __shared__ unsigned short Bs[128 * 40];
  int tid = threadIdx.x;
  int wave = tid >> 6, lane = tid & 63;
  int wm = (wave >> 1) * (MT / 2), wn = (wave & 1) * 64;
  int quad = lane >> 4, l15 = lane & 15;
  int bm = blockIdx.y * MT, bn = blockIdx.x * 128;
  int sr = tid >> 2, sq = tid & 3;

  floatx4 zero = {0.f, 0.f, 0.f, 0.f};
  floatx4 acc[FI][4];
#pragma unroll
  for (int fi = 0; fi < FI; fi++)
#pragma unroll
    for (int fj = 0; fj < 4; fj++) acc[fi][fj] = zero;

  // prefetch chunk 0
  uint4 av0, av1, bv0, bv1;
  av0 = *(const uint4*)(A + (size_t)(bm + sr) * K + sq * 8);
  if (MT == 128) av1 = *(const uint4*)(A + (size_t)(bm + 64 + sr) * K + sq * 8);
  bv0 = *(const uint4*)(Bw + (size_t)(bn + sr) * K + sq * 8);
  bv1 = *(const uint4*)(Bw + (size_t)(bn + 64 + sr) * K + sq * 8);

  for (int k0 = 0; k0 < K; k0 += 32) {
    __syncthreads();
    *(uint4*)(As + sr * 40 + sq * 8) = av0;
    if (MT == 128) *(uint4*)(As + (64 + sr) * 40 + sq * 8) = av1;
    *(uint4*)(Bs + sr * 40 + sq * 8) = bv0;
    *(uint4*)(Bs + (64 + sr) * 40 + sq * 8) = bv1;
    __syncthreads();
    if (k0 + 32 < K) {  // prefetch next chunk while MFMAs run
      av0 = *(const uint4*)(A + (size_t)(bm + sr) * K + k0 + 32 + sq * 8);
      if (MT == 128) av1 = *(const uint4*)(A + (size_t)(bm + 64 + sr) * K + k0 + 32 + sq * 8);
      bv0 = *(const uint4*)(Bw + (size_t)(bn + sr) * K + k0 + 32 + sq * 8);
      bv1 = *(const uint4*)(Bw + (size_t)(bn + 64 + sr) * K + k0 + 32 + sq * 8);
    }
    short8 af[FI], bf[4];
#pragma unroll
    for (int f = 0; f < FI; f++) af[f] = *(const short8*)(As + (wm + f * 16 + l15) * 40 + quad * 8);
#pragma unroll
    for (int f = 0; f < 4; f++) bf[f] = *(const short8*)(Bs + (wn + f * 16 + l15) * 40 + quad * 8);
#pragma unroll
    for (int fi = 0; fi < FI; fi++)
#pragma unroll
      for (int fj = 0; fj < 4; fj++)
        acc[fi][fj] = __builtin_amdgcn_mfma_f32_16x16x32_bf16(af[fi], bf[fj], acc[fi][fj], 0, 0, 0);
  }

#pragma unroll
  for (int fi = 0; fi < FI; fi++) {
#pragma unroll
    for (int fj = 0; fj < 4; fj++) {
      int col = bn + wn + fj * 16 + l15;
      float bb = BIAS ? bias[col] : 0.f;
#pragma unroll
      for (int rg = 0; rg < 4; rg++) {
        int row = bm + wm + fi * 16 + quad * 4 + rg;
        float v = acc[fi][fj][rg] + bb;
        if (RES) v += Res[(size_t)row * N + col];
        if (RELU) v = fmaxf(v, 0.f);
        if (OUT_BF16) Cb[(size_t)row * N + col] = f2bf(v);
        else Cf[(size_t)row * N + col] = v;
      }
    }
  }
}

// ---------------- KPROJ with fused LayerNorm:
// hn = LN(x); k = hn @ [Wsem;Wepi]^T; khat fp32 (granule-permuted) + raw kT ----------------
// NOTE: kT must NOT alias hx — hx is read by concurrent blocks while the epilogue
// writes kT (cross-block WAR race if aliased; R6/R7 lesson). kT now lives in the
// dead hbf+hnb region.
__global__ __launch_bounds__(256) void kproj_kernel(const float* __restrict__ hx,
                                                    const float* __restrict__ gma,
                                                    const float* __restrict__ bta,
                                                    const unsigned short* __restrict__ Wcb,
                                                    float* __restrict__ khat,
                                                    float* __restrict__ kT) {
  __shared__ unsigned short As[32 * 40];
  __shared__ unsigned short Bs[256 * 40];
  __shared__ float mus[32], ivs[32];
  int tid = threadIdx.x;
  int wave = tid >> 6, lane = tid & 63;
  int wm = (wave >> 1) * 16, wnh = wave & 1, wn = wnh * 128;
  int quad = lane >> 4, l15 = lane & 15;
  int bm = blockIdx.x * 32;

  // ---- LN stats for rows bm..bm+31 (8 threads per row; 8-lane DPP reduce)
  {
    int row = tid >> 3, jj = tid & 7;
    const float4* hr = (const float4*)(hx + (size_t)(bm + row) * H_ + jj * 32);
    float s = 0.f, sq = 0.f;
#pragma unroll
    for (int q = 0; q < 8; q++) {
      float4 v = hr[q];
      s += (v.x + v.y) + (v.z + v.w);
      sq += (v.x * v.x + v.y * v.y) + (v.z * v.z + v.w * v.w);
    }
    s = dpp_xor_add<0xB1>(s);  sq = dpp_xor_add<0xB1>(sq);
    s = dpp_xor_add<0x4E>(s);  sq = dpp_xor_add<0x4E>(sq);
    s = dpp_xor_add<0x141>(s); sq = dpp_xor_add<0x141>(sq);
    float mu = s * (1.f / H_);
    float var = sq * (1.f / H_) - mu * mu;
    if (jj == 0) { mus[row] = mu; ivs[row] = rsqrtf(var + 1e-5f); }
  }
  // mus/ivs are ordered before As staging by the loop-top __syncthreads().

  floatx4 zero = {0.f, 0.f, 0.f, 0.f};
  floatx4 acc[8];
#pragma unroll
  for (int fj = 0; fj < 8; fj++) acc[fj] = zero;

  int sr = tid >> 2, sq4 = tid & 3;
  // prefetch chunk 0: A fp32 + gamma/beta (per-column) + B bf16
  float4 af0, af1, gf0, gf1, bt0, bt1;
  uint4 bv[4];
  if (tid < 128) {
    const float4* ap = (const float4*)(hx + (size_t)(bm + sr) * H_ + sq4 * 8);
    af0 = ap[0]; af1 = ap[1];
    const float4* gp = (const float4*)(gma + sq4 * 8); gf0 = gp[0]; gf1 = gp[1];
    const float4* bp = (const float4*)(bta + sq4 * 8); bt0 = bp[0]; bt1 = bp[1];
  }
#pragma unroll
  for (int q = 0; q < 4; q++) {
    int unit = q * 256 + tid;
    bv[q] = *(const uint4*)(Wcb + (size_t)(unit >> 2) * H_ + (unit & 3) * 8);
  }

  for (int k0 = 0; k0 < 256; k0 += 32) {
    __syncthreads();
    if (tid < 128) {  // normalize + cast + stage A
      float mu = mus[sr], iv = ivs[sr];
      ushort4 lo, hi;
      lo.x = f2bf((af0.x - mu) * iv * gf0.x + bt0.x);
      lo.y = f2bf((af0.y - mu) * iv * gf0.y + bt0.y);
      lo.z = f2bf((af0.z - mu) * iv * gf0.z + bt0.z);
      lo.w = f2bf((af0.w - mu) * iv * gf0.w + bt0.w);
      hi.x = f2bf((af1.x - mu) * iv * gf1.x + bt1.x);
      hi.y = f2bf((af1.y - mu) * iv * gf1.y + bt1.y);
      hi.z = f2bf((af1.z - mu) * iv * gf1.z + bt1.z);
      hi.w = f2bf((af1.w - mu) * iv * gf1.w + bt1.w);
      *(ushort4*)(As + sr * 40 + sq4 * 8) = lo;
      *(ushort4*)(As + sr * 40 + sq4 * 8 + 4) = hi;
    }
#pragma unroll
    for (int q = 0; q < 4; q++) {
      int unit = q * 256 + tid;
      *(uint4*)(Bs + (unit >> 2) * 40 + (unit & 3) * 8) = bv[q];
    }
    __syncthreads();
    if (k0 + 32 < 256) {
      if (tid < 128) {
        const float4* ap = (const float4*)(hx + (size_t)(bm + sr) * H_ + k0 + 32 + sq4 * 8);
        af0 = ap[0]; af1 = ap[1];
        const float4* gp = (const float4*)(gma + k0 + 32 + sq4 * 8); gf0 = gp[0]; gf1 = gp[1];
        const float4* bp = (const float4*)(bta + k0 + 32 + sq4 * 8); bt0 = bp[0]; bt1 = bp[1];
      }
#pragma unroll
      for (int q = 0; q < 4; q++) {
        int unit = q * 256 + tid;
        bv[q] = *(const uint4*)(Wcb + (size_t)(unit >> 2) * H_ + k0 + 32 + (unit & 3) * 8);
      }
    }
    short8 af = *(const short8*)(As + (wm + l15) * 40 + quad * 8);
    short8 bf[8];
#pragma unroll
    for (int fj = 0; fj < 8; fj++)
      bf[fj] = *(const short8*)(Bs + (wn + fj * 16 + l15) * 40 + quad * 8);
#pragma unroll
    for (int fj = 0; fj < 8; fj++)
      acc[fj] = __builtin_amdgcn_mfma_f32_16x16x32_bf16(af, bf[fj], acc[fj], 0, 0, 0);
  }

  // epilogue: per-row L2 norm over this wave's 128-col half
  int b = bm >> 9;
  int idxm = b * 2 + wnh;
  int tloc0 = (bm & 511) + wm + quad * 4;
  float inv[4];
#pragma unroll
  for (int rg = 0; rg < 4; rg++) {
    float ssq = 0.f;
#pragma unroll
    for (int fj = 0; fj < 8; fj++) ssq += acc[fj][rg] * acc[fj][rg];
    ssq = redu16(ssq);
    inv[rg] = 1.f / fmaxf(sqrtf(ssq), 1e-12f);
  }
#pragma unroll
  for (int fj = 0; fj < 8; fj++) {
    int ch = fj * 16 + l15;             // logical col 0..127
    int j = ch >> 2, e = ch & 3;        // float4 granule + elem
    int pj = (j & 1) ? (16 + (j >> 1)) : (j >> 1);  // even granules first
    int pcol = pj * 4 + e;
#pragma unroll
    for (int rg = 0; rg < 4; rg++)
      khat[((size_t)idxm * L_ + tloc0 + rg) * HALF_ + pcol] = acc[fj][rg] * inv[rg];
    float4 raw = {acc[fj][0], acc[fj][1], acc[fj][2], acc[fj][3]};
    *(float4*)(kT + (size_t)idxm * (HALF_ * L_) + (size_t)ch * L_ + tloc0) = raw;
  }
}

// ---------------- scan: LDS-staged khat (async), 4-deep ds_read ring (R0-proven) ----------------
#define STEP(KP, KR)                                                     \
  do {                                                                   \
    float t0_ = m[0] * KP[0] + m[1] * KP[1];                             \
    float t1_ = m[2] * KP[2] + m[3] * KP[3];                             \
    float t2_ = m[4] * KP[4] + m[5] * KP[5];                             \
    float t3_ = m[6] * KP[6] + m[7] * KP[7];                             \
    float p_ = (t0_ + t1_) + (t2_ + t3_);                                \
    p_ = redu16(p_);                                                     \
    float s_ = (KR) - p_;                                                \
    m[0] += s_ * KP[0]; m[1] += s_ * KP[1]; m[2] += s_ * KP[2];          \
    m[3] += s_ * KP[3]; m[4] += s_ * KP[4]; m[5] += s_ * KP[5];          \
    m[6] += s_ * KP[6]; m[7] += s_ * KP[7];                              \
  } while (0)

__global__ __launch_bounds__(256) void scan_kernel(const float* __restrict__ khat,
                                                   const float* __restrict__ kT,
                                                   float* __restrict__ c) {
  __shared__ float sk[2][64 * 128];  // 2 x 32 KB double buffer
  int bid = blockIdx.x;
  int idxm = bid & 31;
  int rg = bid >> 5;
  int b = idxm >> 1, mat = idxm & 1;
  const float* kh = khat + (size_t)idxm * L_ * HALF_;
  const float* kTi = kT + (size_t)idxm * HALF_ * L_;

  int tid = threadIdx.x;
  int wave = tid >> 6, lane = tid & 63;
  int seg = tid & 15, rl = tid >> 4;
  int r = rg * 16 + rl;
  int c0 = seg * 8;
  const float* krow = kTi + (size_t)r * L_;

  float m[8];
#pragma unroll
  for (int g = 0; g < 8; g++) m[g] = 0.f;

  // stage chunk 0 into buf 0
  {
    const float* g0 = kh + wave * 2048 + lane * 4;
    float* l0 = &sk[0][wave * 2048];
#pragma unroll
    for (int j = 0; j < 8; j++) async_cp16(g0 + j * 256, l0 + j * 256);
  }
  __syncthreads();

  float4 krn = *(const float4*)(krow);  // raw keys, steps 0..3
  const float* lb = &sk[0][0] + seg * 4;

  // chunks 0..6 (full 64 steps each)
  for (int ch = 0; ch < 7; ch++) {
    {  // stage chunk ch+1 into the other buffer (async, drains at end-of-chunk barrier)
      const float* gs = kh + (size_t)(ch + 1) * 8192 + wave * 2048 + lane * 4;
      float* ls = &sk[(ch + 1) & 1][wave * 2048];
#pragma unroll
      for (int j = 0; j < 8; j++) async_cp16(gs + j * 256, ls + j * 256);
    }
    const float* base = lb + (ch & 1) * 8192;
    float pk[4][8];
#pragma unroll
    for (int u = 0; u < 4; u++) {
      *(float4*)&pk[u][0] = *(const float4*)(base + u * 128);
      *(float4*)&pk[u][4] = *(const float4*)(base + u * 128 + 64);
    }
    for (int g = 0; g < 15; g++) {
      float4 krc = krn;
      krn = *(const float4*)(krow + ch * 64 + g * 4 + 4);
#pragma unroll
      for (int u = 0; u < 4; u++) {
        STEP(pk[u], ((u == 0) ? krc.x : (u == 1) ? krc.y : (u == 2) ? krc.z : krc.w));
        int tn = g * 4 + u + 4;
        *(float4*)&pk[u][0] = *(const float4*)(base + tn * 128);
        *(float4*)&pk[u][4] = *(const float4*)(base + tn * 128 + 64);
      }
    }
    {  // last 4 steps of chunk, no prefetch
      float4 krc = krn;
      krn = *(const float4*)(krow + ch * 64 + 64);
      STEP(pk[0], krc.x);
      STEP(pk[1], krc.y);
      STEP(pk[2], krc.z);
      STEP(pk[3], krc.w);
    }
    __syncthreads();
  }

  // chunk 7: steps 448..510 (63 updates)
  {
    const float* base = lb + 8192;  // buf 1
    float pk[4][8];
#pragma unroll
    for (int u = 0; u < 4; u++) {
      *(float4*)&pk[u][0] = *(const float4*)(base + u * 128);
      *(float4*)&pk[u][4] = *(const float4*)(base + u * 128 + 64);
    }
    for (int g = 0; g < 15; g++) {
      float4 krc = krn;
      krn = *(const float4*)(krow + 448 + g * 4 + 4);
#pragma unroll
      for (int u = 0; u < 4; u++) {
        STEP(pk[u], ((u == 0) ? krc.x : (u == 1) ? krc.y : (u == 2) ? krc.z : krc.w));
        int tn = g * 4 + u + 4;
        *(float4*)&pk[u][0] = *(const float4*)(base + tn * 128);
        *(float4*)&pk[u][4] = *(const float4*)(base + tn * 128 + 64);
      }
    }
    float4 krc = krn;  // raw keys for steps 508..511
    STEP(pk[0], krc.x);  // 508
    STEP(pk[1], krc.y);  // 509
    STEP(pk[2], krc.z);  // 510
  }

  // final read with raw last-token key (t=511), gathered from kT columns
  float q[8];
#pragma unroll
  for (int j = 0; j < 8; j++) q[j] = kTi[(size_t)(c0 + j) * L_ + 511];
  float t0 = m[0] * q[0] + m[1] * q[1];
  float t1 = m[2] * q[2] + m[3] * q[3];
  float t2 = m[4] * q[4] + m[5] * q[5];
  float t3 = m[6] * q[6] + m[7] * q[7];
  float p = redu16((t0 + t1) + (t2 + t3));
  if (seg == 0) c[(size_t)b * H_ + mat * HALF_ + r] = p;
}

// ---------------- r = c @ W_rp^T + b_rp ----------------
__global__ void rp_kernel(const float* __restrict__ c, const float* __restrict__ Wrp,
                          const float* __restrict__ brp, float* __restrict__ r) {
  int b = blockIdx.x;
  int n = threadIdx.x;  // 256
  __shared__ float cs[H_];
  cs[n] = c[(size_t)b * H_ + n];
  __syncthreads();
  const float4* w4 = (const float4*)(Wrp + (size_t)n * H_);
  const float4* c4 = (const float4*)cs;
  float acc = 0.f;
#pragma unroll 8
  for (int k = 0; k < H_ / 4; k++) {
    float4 w = w4[k], cc = c4[k];
    acc += w.x * cc.x + w.y * cc.y + w.z * cc.z + w.w * cc.w;
  }
  r[(size_t)b * H_ + n] = acc + brp[n];
}

// ---------------- out = r @ W_out^T + b_out, coalesced (R6-proven) ----------------
__global__ __launch_bounds__(256) void out_kernel(const float* __restrict__ r,
                                                  const float* __restrict__ Wout,
                                                  const float* __restrict__ bout,
                                                  float* __restrict__ out) {
  __shared__ float rs[16 * 272];
  __shared__ float obuf[16 * 68];
  int tid = threadIdx.x;
#pragma unroll
  for (int q = 0; q < 16; q++) {
    int idx = q * 256 + tid;
    int bb = idx >> 8, cc = idx & 255;
    rs[bb * 272 + cc + 4 * (cc >> 6)] = r[idx];
  }
  __syncthreads();
  int row = tid >> 2, part = tid & 3;
  int v = blockIdx.x * 64 + row;
  const float4* w4 = (const float4*)(Wout + (size_t)v * H_ + part * 64);
  float acc[16];
#pragma unroll
  for (int bb = 0; bb < 16; bb++) acc[bb] = 0.f;
#pragma unroll 4
  for (int j = 0; j < 16; j++) {
    float4 w = w4[j];
#pragma unroll
    for (int bb = 0; bb < 16; bb++) {
      float4 rv = *(const float4*)&rs[bb * 272 + part * 68 + j * 4];
      acc[bb] += w.x * rv.x + w.y * rv.y + w.z * rv.z + w.w * rv.w;
    }
  }
  float bo = bout[v];
#pragma unroll
  for (int bb = 0; bb < 16; bb++) {
    acc[bb] = dpp_xor_add<0xB1>(acc[bb]);
    acc[bb] = dpp_xor_add<0x4E>(acc[bb]);
  }
#pragma unroll
  for (int q = 0; q < 4; q++) {
    int bb = part * 4 + q;
    obuf[bb * 68 + row] = acc[bb] + bo;
  }
  __syncthreads();
#pragma unroll
  for (int q = 0; q < 4; q++) {
    int idx = q * 256 + tid;
    int bb = idx >> 6, vl = idx & 63;
    out[(size_t)bb * V_ + blockIdx.x * 64 + vl] = obuf[bb * 68 + vl];
  }
}

extern "C" void kernel_launch(void* const* d_in, const int* in_sizes, int n_in,
                              void* d_out, int out_size, void* d_ws, size_t ws_size,
                              hipStream_t stream) {
  const int* seq = (const int*)d_in[0];
  const float* embed = (const float*)d_in[1];
  const float* W1 = (const float*)d_in[2];
  const float* b1 = (const float*)d_in[3];
  const float* W2 = (const float*)d_in[4];
  const float* b2 = (const float*)d_in[5];
  const float* gamma = (const float*)d_in[6];
  const float* beta = (const float*)d_in[7];
  const float* Wsem = (const float*)d_in[8];
  const float* Wepi = (const float*)d_in[9];
  const float* Wrp = (const float*)d_in[10];
  const float* brp = (const float*)d_in[11];
  const float* Wout = (const float*)d_in[12];
  const float* bout = (const float*)d_in[13];
  float* out = (float*)d_out;

  // Workspace layout (float-slot offsets) — alias-free schedule:
  //  [0        , 2097152 )  h fp32 (x in-place; read by gemm2 Res and kproj hx)
  //  [2097152  , 4194304 )  a1b bf16 [8192,512]  -> later khat (a1b dead after gemm2)
  //  [4194304  , 5242880 )  hbf bf16 [8192,256]  (dead after gemm1)
  //  [4194304  , 6291456 )  kT fp32 [32,128,512] (kproj writes over dead hbf+gap;
  //                                               does NOT alias h — cross-block race fix)
  //  [6291456  , 6356992 )  W1b bf16 131072
  //  [6356992  , 6422528 )  W2b bf16 131072
  //  [6422528  , 6455296 )  Wcb bf16 65536
  //  [6455296  , 6459392 )  c  [16,256]
  //  [6459392  , 6463488 )  r  [16,256]
  float* ws = (float*)d_ws;
  float* h = ws;
  unsigned short* a1b = (unsigned short*)(ws + 2097152);
  float* khat = ws + 2097152;
  unsigned short* hbf = (unsigned short*)(ws + 4194304);
  float* kT = ws + 4194304;
  unsigned short* W1b = (unsigned short*)(ws + 6291456);
  unsigned short* W2b = (unsigned short*)(ws + 6356992);
  unsigned short* Wcb = (unsigned short*)(ws + 6422528);
  float* c = ws + 6455296;
  float* r = ws + 6459392;

  // 1. gather (h fp32 + hbf bf16) + weight conversion
  prep_kernel<<<3328, 256, 0, stream>>>(seq, embed, h, hbf, W1, W2, Wsem, Wepi, W1b, W2b, Wcb);
  // 2. a1 = relu(h @ W1^T + b1) -> bf16
  gemm_mfma<128, true, true, false, true><<<dim3(4, 64), 256, 0, stream>>>(
      hbf, W1b, b1, nullptr, nullptr, a1b, 8192, 512, 256);
  // 3. x = a1 @ W2^T + b2 + h -> fp32 in-place over h
  gemm_mfma<64, false, true, true, false><<<dim3(2, 128), 256, 0, stream>>>(
      a1b, W2b, b2, h, h, nullptr, 8192, 256, 512);
  // 4+5. fused LayerNorm + k-projection + normalize + permute/transpose
  kproj_kernel<<<256, 256, 0, stream>>>(h, gamma, beta, Wcb, khat, kT);
  // 6. delta-rule scan -> c [16,256]
  scan_kernel<<<256, 256, 0, stream>>>(khat, kT, c);
  // 7. r = c @ Wrp^T + brp
  rp_kernel<<<16, 256, 0, stream>>>(c, Wrp, brp, r);
  // 8. out = r @ Wout^T + bout
  out_kernel<<<500, 256, 0, stream>>>(r, Wout, bout, out);
}